// Round 2
// baseline (357.487 us; speedup 1.0000x reference)
//
#include <hip/hip_runtime.h>

// Problem constants: T=2048, B=8, IN=1024, OUT=1024, N_MODULES=16, K=2
#define T_DIM   2048
#define B_DIM   8
#define IN_DIM  1024
#define OUT_DIM 1024
#define NMOD    16
#define KSLOT   2

// 8-phase 256x256 schedule (m201 template): BK=64, 8 waves (2M x 4N), 512 thr
// R2: persistent ks-pair -- each block computes (mt,nt,b,ks=0) then ks=1 with
// a CONTINUOUS 32-group staging pipeline (A panel shared; B expert switches at
// v=16). Grid = 256 = 1 block/CU, one round; no mid-kernel pipeline drain.
#define BM 256
#define BN 256
#define BK 64
#define NT (IN_DIM / BK)            // 16 K-tiles per output tile
#define NU (2 * NT)                 // 32 groups total (ks=0 then ks=1)
#define AS_STRIDE (B_DIM * IN_DIM)  // 8192

typedef __bf16 bf16x8 __attribute__((ext_vector_type(8)));
typedef float  f32x4  __attribute__((ext_vector_type(4)));
typedef unsigned short ushort8 __attribute__((ext_vector_type(8)));

typedef const __attribute__((address_space(1))) void* gptr_t;
typedef __attribute__((address_space(3))) void* lptr_t;

__device__ __forceinline__ void async_load16(const void* gp, void* lp) {
  __builtin_amdgcn_global_load_lds((gptr_t)gp, (lptr_t)lp, 16, 0, 0);
}

// fp32 -> bf16 round-to-nearest-even (inputs have no NaNs)
__device__ __forceinline__ unsigned short f2bf_rne(float f) {
  unsigned int u = __float_as_uint(f);
  u += 0x7fffu + ((u >> 16) & 1u);
  return (unsigned short)(u >> 16);
}

// Streaming prepass: x [T][B][IN] fp32 -> xb same layout bf16; w -> wb bf16.
__global__ __launch_bounds__(256) void convert_bf16(
    const float* __restrict__ x, const float* __restrict__ w,
    unsigned short* __restrict__ xb, unsigned short* __restrict__ wb) {
  const long tid = (long)blockIdx.x * blockDim.x + threadIdx.x;
  const long XV = (long)T_DIM * B_DIM * IN_DIM / 8;
  const float4* src;
  unsigned short* dst;
  long v;
  if (tid < XV) { v = tid;      src = (const float4*)x; dst = xb; }
  else          { v = tid - XV; src = (const float4*)w; dst = wb; }
  float4 a = src[2 * v];
  float4 c = src[2 * v + 1];
  ushort8 o;
  o[0] = f2bf_rne(a.x); o[1] = f2bf_rne(a.y); o[2] = f2bf_rne(a.z); o[3] = f2bf_rne(a.w);
  o[4] = f2bf_rne(c.x); o[5] = f2bf_rne(c.y); o[6] = f2bf_rne(c.z); o[7] = f2bf_rne(c.w);
  *(ushort8*)(dst + v * 8) = o;
}

#define S_BARRIER()  asm volatile("s_barrier" ::: "memory")
#define WAIT_LGKM0() asm volatile("s_waitcnt lgkmcnt(0)" ::: "memory")

// Per block: C[t,o] = sum_i xb[t][b][i] * wb[sel[2b+ks]][o][i] for ks=0,1.
//
// 8-phase schedule per K-tile group (4 phases x 2 barriers), counted vmcnt
// (never 0 until the final 2 groups). LDS: 2 dbuf x (A 256x64 + B 256x64)
// bf16 = 128 KiB, 16-B chunks with source-side XOR swizzle (slot s of row r
// holds colgrp s^(r&7)); reads slot gsel^(row&7) -> conflict-free (verified).
//
// Half-tile regions (union over waves of per-phase reads):
//   A-a rows [0,64)u[128,192)  (P0)    A-b rows [64,128)u[192,256) (P2)
//   B-a rows ==[0,32) mod 64   (P0; regs held to P3)
//   B-b rows ==[32,64) mod 64  (P1)
// Group u stages (u+1).Ba at P0 (nxt buf) and (u+2).{Aa,Bb,Ab} at P1/P2/P3
// (cur buf); vmcnt(6) at P3 leaves exactly the 3 newest half-stages in
// flight => group u+1's tile fully landed. Staging index v runs 0..31
// continuously across the ks boundary (K offset = (v&15)*BK; B base switches
// expert at v>=16), so the pipeline never drains mid-kernel. The ks=0
// accumulator is stored at u==NT; its store drain (L2-accept) overlaps
// tile-2's first phases before the u=16 vmcnt gate conservatively waits it.
__global__ __launch_bounds__(512, 2) void gemm_mod(
    const unsigned short* __restrict__ xb, const unsigned short* __restrict__ wb,
    const int* __restrict__ sel, float* __restrict__ out) {
  __shared__ alignas(16) unsigned short As[2][BM * BK];   // 64 KiB
  __shared__ alignas(16) unsigned short Bs[2][BN * BK];   // 64 KiB

  const int nt = blockIdx.x;           // OUT tile: 0..3
  const int mt = blockIdx.y;           // T tile:   0..7
  const int b  = blockIdx.z;           // batch:    0..7
  const int e0 = sel[2 * b];
  const int e1 = sel[2 * b + 1];

  const unsigned short* Ab  = xb + ((long)mt * BM * B_DIM + b) * IN_DIM;
  const unsigned short* Bw0 = wb + ((long)e0 * OUT_DIM + (long)nt * BN) * IN_DIM;
  const unsigned short* Bw1 = wb + ((long)e1 * OUT_DIM + (long)nt * BN) * IN_DIM;

  const int tid  = threadIdx.x;
  const int lane = tid & 63;
  const int lm   = lane & 15;          // MFMA m/n index
  const int kg   = lane >> 4;          // MFMA k-group (0..3)
  const int rsw  = lm & 7;             // row-derived swizzle term
  const int w    = tid >> 6;           // 8 waves: 2(M) x 4(N)
  const int wm   = (w >> 2) * 128;     // wave tile 128 x 64
  const int wn   = (w & 3) * 64;

  // Staging offsets [j][h] (2 x global_load_lds per half-tile per thread).
  int aoff[2][2], alds[2][2], boff[2][2], blds[2][2];
  #pragma unroll
  for (int j = 0; j < 2; ++j) {
    #pragma unroll
    for (int h = 0; h < 2; ++h) {
      const int c = j * 1024 + h * 512 + tid;
      const int r = c >> 3, g = (c & 7) ^ (r & 7);
      aoff[j][h] = r * AS_STRIDE + g * 8;
      alds[j][h] = c * 8;
      const int cc = j * 512 + tid;
      const int c2 = (cc >> 8) * 512 + h * 256 + (cc & 255);
      const int r2 = c2 >> 3, g2 = (c2 & 7) ^ (r2 & 7);
      boff[j][h] = r2 * IN_DIM + g2 * 8;
      blds[j][h] = c2 * 8;
    }
  }

#define KOF(v) (((v) & (NT - 1)) * BK)
#define STAGE_A(d, v, h) do { \
    async_load16(Ab + aoff[0][h] + KOF(v), &As[d][alds[0][h]]); \
    async_load16(Ab + aoff[1][h] + KOF(v), &As[d][alds[1][h]]); } while (0)
#define STAGE_B(d, v, h) do { \
    const unsigned short* _bs = ((v) < NT ? Bw0 : Bw1); \
    async_load16(_bs + boff[0][h] + KOF(v), &Bs[d][blds[0][h]]); \
    async_load16(_bs + boff[1][h] + KOF(v), &Bs[d][blds[1][h]]); } while (0)
#define LDA(d, row, gs) (*(const bf16x8*)&As[d][((((row) << 3) + ((gs) ^ rsw)) << 3)])
#define LDB(d, row, gs) (*(const bf16x8*)&Bs[d][((((row) << 3) + ((gs) ^ rsw)) << 3)])

  f32x4 acc[8][4];
  const f32x4 z = {0.f, 0.f, 0.f, 0.f};
  #pragma unroll
  for (int i = 0; i < 8; ++i)
    #pragma unroll
    for (int j = 0; j < 4; ++j) acc[i][j] = z;

  const int row0 = mt * BM + wm + kg * 4;
  const int col0 = nt * BN + wn + lm;
#define STORE_TILE(ksl) do { \
    _Pragma("unroll") \
    for (int mi = 0; mi < 8; ++mi) { \
      _Pragma("unroll") \
      for (int r = 0; r < 4; ++r) { \
        const int tr = row0 + mi * 16 + r; \
        float* po = out + (long)tr * (B_DIM * KSLOT * OUT_DIM) \
                        + b * (KSLOT * OUT_DIM) + (ksl) * OUT_DIM + col0; \
        _Pragma("unroll") \
        for (int ni = 0; ni < 4; ++ni) po[ni * 16] = acc[mi][ni][r]; \
      } } } while (0)

  // ---- prologue: v0 all 4 halves + v1 first 3 (order: Aa, Bb, Ab, Ba) ----
  STAGE_A(0, 0, 0);
  STAGE_B(0, 0, 1);
  STAGE_A(0, 0, 1);
  STAGE_B(0, 0, 0);
  STAGE_A(1, 1, 0);
  STAGE_B(1, 1, 1);
  STAGE_A(1, 1, 1);
  asm volatile("s_waitcnt vmcnt(6)" ::: "memory");   // v0 landed; v1 x3 in flight
  S_BARRIER();

  #pragma unroll 2
  for (int u = 0; u < NU; ++u) {
    if (u == NT) {                     // tile-1 (ks=0) complete: dump + reset
      STORE_TILE(0);
      #pragma unroll
      for (int i = 0; i < 8; ++i)
        #pragma unroll
        for (int j = 0; j < 4; ++j) acc[i][j] = z;
    }
    const int cur = u & 1;
    const int nxt = cur ^ 1;
    bf16x8 af[4][2], b0[2][2], b1[2][2];

    // ===== P0: read A-a (8) + B-a (4); stage (u+1).Ba -> nxt =====
    #pragma unroll
    for (int mi = 0; mi < 4; ++mi)
      #pragma unroll
      for (int kst = 0; kst < 2; ++kst)
        af[mi][kst] = LDA(cur, wm + mi * 16 + lm, kst * 4 + kg);
    #pragma unroll
    for (int ni = 0; ni < 2; ++ni)
      #pragma unroll
      for (int kst = 0; kst < 2; ++kst)
        b0[ni][kst] = LDB(cur, wn + ni * 16 + lm, kst * 4 + kg);
    if (u + 1 < NU) STAGE_B(nxt, u + 1, 0);
    S_BARRIER();
    WAIT_LGKM0();
    __builtin_amdgcn_s_setprio(1);
    #pragma unroll
    for (int mi = 0; mi < 4; ++mi)
      #pragma unroll
      for (int ni = 0; ni < 2; ++ni)
        #pragma unroll
        for (int kst = 0; kst < 2; ++kst)
          acc[mi][ni] = __builtin_amdgcn_mfma_f32_16x16x32_bf16(
              af[mi][kst], b0[ni][kst], acc[mi][ni], 0, 0, 0);
    __builtin_amdgcn_s_setprio(0);
    S_BARRIER();

    // ===== P1: read B-b (4); stage (u+2).Aa -> cur =====
    #pragma unroll
    for (int nj = 0; nj < 2; ++nj)
      #pragma unroll
      for (int kst = 0; kst < 2; ++kst)
        b1[nj][kst] = LDB(cur, wn + (2 + nj) * 16 + lm, kst * 4 + kg);
    if (u + 2 < NU) STAGE_A(cur, u + 2, 0);
    S_BARRIER();
    WAIT_LGKM0();
    __builtin_amdgcn_s_setprio(1);
    #pragma unroll
    for (int mi = 0; mi < 4; ++mi)
      #pragma unroll
      for (int nj = 0; nj < 2; ++nj)
        #pragma unroll
        for (int kst = 0; kst < 2; ++kst)
          acc[mi][2 + nj] = __builtin_amdgcn_mfma_f32_16x16x32_bf16(
              af[mi][kst], b1[nj][kst], acc[mi][2 + nj], 0, 0, 0);
    __builtin_amdgcn_s_setprio(0);
    S_BARRIER();

    // ===== P2: read A-b (8); stage (u+2).Bb -> cur =====
    #pragma unroll
    for (int mi = 0; mi < 4; ++mi)
      #pragma unroll
      for (int kst = 0; kst < 2; ++kst)
        af[mi][kst] = LDA(cur, wm + 64 + mi * 16 + lm, kst * 4 + kg);
    if (u + 2 < NU) STAGE_B(cur, u + 2, 1);
    S_BARRIER();
    WAIT_LGKM0();
    __builtin_amdgcn_s_setprio(1);
    #pragma unroll
    for (int mi = 0; mi < 4; ++mi)
      #pragma unroll
      for (int nj = 0; nj < 2; ++nj)
        #pragma unroll
        for (int kst = 0; kst < 2; ++kst)
          acc[4 + mi][2 + nj] = __builtin_amdgcn_mfma_f32_16x16x32_bf16(
              af[mi][kst], b1[nj][kst], acc[4 + mi][2 + nj], 0, 0, 0);
    __builtin_amdgcn_s_setprio(0);
    S_BARRIER();

    // ===== P3: no reads (b0 held); stage (u+2).Ab -> cur; vmcnt gate =====
    if (u + 2 < NU) STAGE_A(cur, u + 2, 1);
    __builtin_amdgcn_s_setprio(1);
    #pragma unroll
    for (int mi = 0; mi < 4; ++mi)
      #pragma unroll
      for (int ni = 0; ni < 2; ++ni)
        #pragma unroll
        for (int kst = 0; kst < 2; ++kst)
          acc[4 + mi][ni] = __builtin_amdgcn_mfma_f32_16x16x32_bf16(
              af[mi][kst], b0[ni][kst], acc[4 + mi][ni], 0, 0, 0);
    __builtin_amdgcn_s_setprio(0);
    if (u < NU - 2) {
      asm volatile("s_waitcnt vmcnt(6)" ::: "memory");  // 3 newest halves fly
    } else {
      asm volatile("s_waitcnt vmcnt(0)" ::: "memory");  // tail drain (u=30,31)
    }
    S_BARRIER();
  }

  STORE_TILE(1);                        // tile-2 (ks=1)

#undef STAGE_A
#undef STAGE_B
#undef STORE_TILE
#undef LDA
#undef LDB
#undef KOF
}

extern "C" void kernel_launch(void* const* d_in, const int* in_sizes, int n_in,
                              void* d_out, int out_size, void* d_ws, size_t ws_size,
                              hipStream_t stream) {
  const float* x   = (const float*)d_in[0];   // [T][B][IN] fp32
  const int*   sel = (const int*)d_in[1];     // [B][K] int32
  const float* w   = (const float*)d_in[2];   // [NMOD][OUT][IN] fp32
  float* out = (float*)d_out;                 // [T][B][K*OUT] fp32

  unsigned short* xb = (unsigned short*)d_ws;                 // 32 MiB bf16 [T][B][IN]
  unsigned short* wb = xb + (long)T_DIM * B_DIM * IN_DIM;     // 32 MiB bf16 [NMOD][OUT][IN]

  const long total_vecs =
      ((long)T_DIM * B_DIM * IN_DIM + (long)NMOD * OUT_DIM * IN_DIM) / 8;
  convert_bf16<<<dim3((unsigned)((total_vecs + 255) / 256)), 256, 0, stream>>>(x, w, xb, wb);

  dim3 ggrid(OUT_DIM / BN, T_DIM / BM, B_DIM);   // 4 x 8 x 8 = 256 = 1 block/CU
  gemm_mod<<<ggrid, 512, 0, stream>>>(xb, wb, sel, out);
}

// Round 3
// 283.252 us; speedup vs baseline: 1.2621x; 1.2621x over previous
//
#include <hip/hip_runtime.h>

// Problem constants: T=2048, B=8, IN=1024, OUT=1024, N_MODULES=16, K=2
#define T_DIM   2048
#define B_DIM   8
#define IN_DIM  1024
#define OUT_DIM 1024
#define NMOD    16
#define KSLOT   2

// R3: back to the proven m97-style 2-barrier loop (R0, 874 TF-equiv), with
// m105's tile fix (128x256 -> 128x128 = +10.8% measured: 4 blocks/CU resident,
// grid 2048 = two exact full rounds) + T1 XCD-chunked swizzle (each XCD owns
// 2 (b,ks) slots -> both experts L2-resident; A-tile shared across the 8
// consecutive nt-blocks on the same XCD).
#define BM 128
#define BN 128
#define BK 64

typedef __bf16 bf16x8 __attribute__((ext_vector_type(8)));
typedef float  f32x4  __attribute__((ext_vector_type(4)));
typedef unsigned short ushort8 __attribute__((ext_vector_type(8)));

typedef const __attribute__((address_space(1))) void* gptr_t;
typedef __attribute__((address_space(3))) void* lptr_t;

__device__ __forceinline__ void async_load16(const void* gp, void* lp) {
  __builtin_amdgcn_global_load_lds((gptr_t)gp, (lptr_t)lp, 16, 0, 0);
}

// fp32 -> bf16 round-to-nearest-even (inputs have no NaNs)
__device__ __forceinline__ unsigned short f2bf_rne(float f) {
  unsigned int u = __float_as_uint(f);
  u += 0x7fffu + ((u >> 16) & 1u);
  return (unsigned short)(u >> 16);
}

// Streaming prepass: x [T][B][IN] fp32 -> xb same layout bf16; w -> wb bf16.
__global__ __launch_bounds__(256) void convert_bf16(
    const float* __restrict__ x, const float* __restrict__ w,
    unsigned short* __restrict__ xb, unsigned short* __restrict__ wb) {
  const long tid = (long)blockIdx.x * blockDim.x + threadIdx.x;
  const long XV = (long)T_DIM * B_DIM * IN_DIM / 8;
  const float4* src;
  unsigned short* dst;
  long v;
  if (tid < XV) { v = tid;      src = (const float4*)x; dst = xb; }
  else          { v = tid - XV; src = (const float4*)w; dst = wb; }
  float4 a = src[2 * v];
  float4 c = src[2 * v + 1];
  ushort8 o;
  o[0] = f2bf_rne(a.x); o[1] = f2bf_rne(a.y); o[2] = f2bf_rne(a.z); o[3] = f2bf_rne(a.w);
  o[4] = f2bf_rne(c.x); o[5] = f2bf_rne(c.y); o[6] = f2bf_rne(c.z); o[7] = f2bf_rne(c.w);
  *(ushort8*)(dst + v * 8) = o;
}

// One 128x128 tile per block: C[t,o] = sum_i xb[t][b][i] * wb[sel[slot]][o][i]
// LDS row-major [rows][BK] staged as 16-B chunks with source-side XOR swizzle
// (slot s of row r holds colgrp s^(r&7)) -> ds_read_b128 conflict-free
// (verified 0 across R0-R2) while global_load_lds dests stay lane-contiguous.
__global__ __launch_bounds__(256, 4) void gemm_mod(
    const unsigned short* __restrict__ xb, const unsigned short* __restrict__ wb,
    const int* __restrict__ sel, float* __restrict__ out) {
  __shared__ alignas(16) unsigned short As[BM * BK];   // 16 KiB
  __shared__ alignas(16) unsigned short Bs[BN * BK];   // 16 KiB

  // XCD-chunked swizzle: HW round-robins consecutive blockIdx across 8 XCDs;
  // wgid = (bid%8)*256 + bid/8 gives each XCD one contiguous 256-tile chunk
  // = 2 full (b,ks) slots (2 experts = 4 MB bf16 -> fits the 4 MB XCD L2).
  const int wgid = (blockIdx.x & 7) * 256 + (blockIdx.x >> 3);
  const int slot = wgid >> 7;          // 0..15 = b*2+ks
  const int inner = wgid & 127;
  const int mt = inner >> 3;           // T tile:   0..15 (nt-major inside mt
  const int nt = inner & 7;            // OUT tile: 0..7   -> A-tile L2 reuse)
  const int b  = slot >> 1;
  const int ks = slot & 1;
  const int expert = sel[slot];

  const int AS_STRIDE = B_DIM * IN_DIM;  // 8192
  const unsigned short* A  = xb + ((long)mt * BM * B_DIM + b) * IN_DIM;
  const unsigned short* Bw = wb + ((long)expert * OUT_DIM + (long)nt * BN) * IN_DIM;

  const int tid  = threadIdx.x;
  const int lane = tid & 63;

  // A: 1024 chunks -> 4/thread.  B: 1024 chunks -> 4/thread.
  int aoff[4], boff[4], clds[4];
  #pragma unroll
  for (int j = 0; j < 4; ++j) {
    const int c = tid + j * 256;
    const int r = c >> 3;
    const int g = (c & 7) ^ (r & 7);
    aoff[j] = r * AS_STRIDE + g * 8;
    boff[j] = r * IN_DIM + g * 8;
    clds[j] = c * 8;
  }

  const int lm = lane & 15;            // MFMA m/n index
  const int kg = lane >> 4;            // MFMA k-group (0..3)
  const int rsw = lm & 7;              // row-derived swizzle term

  const int wave = tid >> 6;           // 4 waves: 2(M) x 2(N); wave tile 64x64
  const int wm = (wave >> 1) * 64;
  const int wn = (wave & 1) * 64;

  f32x4 acc[4][4];
  const f32x4 z = {0.f, 0.f, 0.f, 0.f};
  #pragma unroll
  for (int i = 0; i < 4; ++i)
    #pragma unroll
    for (int j = 0; j < 4; ++j) acc[i][j] = z;

  for (int kt = 0; kt < IN_DIM; kt += BK) {
    __syncthreads();                   // previous iter's ds_reads done before overwrite
    #pragma unroll
    for (int j = 0; j < 4; ++j)
      async_load16(A + aoff[j] + kt, &As[clds[j]]);
    #pragma unroll
    for (int j = 0; j < 4; ++j)
      async_load16(Bw + boff[j] + kt, &Bs[clds[j]]);
    __syncthreads();                   // drains vmcnt(0) before s_barrier

    #pragma unroll
    for (int kst = 0; kst < 2; ++kst) {  // two K=32 steps inside BK=64
      const int gsel = (kst * 4 + kg);
      bf16x8 af[4], bfr[4];
      #pragma unroll
      for (int mi = 0; mi < 4; ++mi) {
        const int row = wm + mi * 16 + lm;
        af[mi] = *(const bf16x8*)&As[(row * 8 + (gsel ^ rsw)) * 8];
      }
      #pragma unroll
      for (int ni = 0; ni < 4; ++ni) {
        const int row = wn + ni * 16 + lm;
        bfr[ni] = *(const bf16x8*)&Bs[(row * 8 + (gsel ^ rsw)) * 8];
      }
      #pragma unroll
      for (int mi = 0; mi < 4; ++mi)
        #pragma unroll
        for (int ni = 0; ni < 4; ++ni)
          acc[mi][ni] = __builtin_amdgcn_mfma_f32_16x16x32_bf16(af[mi], bfr[ni], acc[mi][ni], 0, 0, 0);
    }
  }

  // Epilogue. C/D layout (m89-verified): col = lane&15, row = (lane>>4)*4 + reg
  const int row0 = mt * BM + wm + kg * 4;
  const int col0 = nt * BN + wn + lm;
  #pragma unroll
  for (int mi = 0; mi < 4; ++mi) {
    #pragma unroll
    for (int r = 0; r < 4; ++r) {
      const int t = row0 + mi * 16 + r;
      float* po = out + (long)t * (B_DIM * KSLOT * OUT_DIM)
                      + b * (KSLOT * OUT_DIM) + ks * OUT_DIM + col0;
      #pragma unroll
      for (int ni = 0; ni < 4; ++ni)
        po[ni * 16] = acc[mi][ni][r];
    }
  }
}

extern "C" void kernel_launch(void* const* d_in, const int* in_sizes, int n_in,
                              void* d_out, int out_size, void* d_ws, size_t ws_size,
                              hipStream_t stream) {
  const float* x   = (const float*)d_in[0];   // [T][B][IN] fp32
  const int*   sel = (const int*)d_in[1];     // [B][K] int32
  const float* w   = (const float*)d_in[2];   // [NMOD][OUT][IN] fp32
  float* out = (float*)d_out;                 // [T][B][K*OUT] fp32

  unsigned short* xb = (unsigned short*)d_ws;                 // 32 MiB bf16 [T][B][IN]
  unsigned short* wb = xb + (long)T_DIM * B_DIM * IN_DIM;     // 32 MiB bf16 [NMOD][OUT][IN]

  const long total_vecs =
      ((long)T_DIM * B_DIM * IN_DIM + (long)NMOD * OUT_DIM * IN_DIM) / 8;
  convert_bf16<<<dim3((unsigned)((total_vecs + 255) / 256)), 256, 0, stream>>>(x, w, xb, wb);

  // 2048 blocks (16 slots x 16 mt x 8 nt), 1D for the XCD swizzle.
  gemm_mod<<<dim3(2048), 256, 0, stream>>>(xb, wb, sel, out);
}

// Round 4
// 274.539 us; speedup vs baseline: 1.3021x; 1.0317x over previous
//
#include <hip/hip_runtime.h>

// Problem constants: T=2048, B=8, IN=1024, OUT=1024, N_MODULES=16, K=2
#define T_DIM   2048
#define B_DIM   8
#define IN_DIM  1024
#define OUT_DIM 1024
#define NMOD    16
#define KSLOT   2

// R4: gemm unchanged from R3 (~74 us ~= 928 TF-equiv, top of the measured
// K=1024 band; 8-phase (R1) and persistent (R2) both measured worse at this
// K). New: convert prepass skips experts not present in sel[] (expected ~5.7
// of 16 skipped -> ~34 MB less HBM traffic). w-region blocks are expert-
// aligned (2^17 vecs per expert, 256 vecs per block), so the skip is a
// uniform per-block branch off one L2-broadcast cacheline.
#define BM 128
#define BN 128
#define BK 64

typedef __bf16 bf16x8 __attribute__((ext_vector_type(8)));
typedef float  f32x4  __attribute__((ext_vector_type(4)));
typedef unsigned short ushort8 __attribute__((ext_vector_type(8)));

typedef const __attribute__((address_space(1))) void* gptr_t;
typedef __attribute__((address_space(3))) void* lptr_t;

__device__ __forceinline__ void async_load16(const void* gp, void* lp) {
  __builtin_amdgcn_global_load_lds((gptr_t)gp, (lptr_t)lp, 16, 0, 0);
}

// fp32 -> bf16 round-to-nearest-even (inputs have no NaNs)
__device__ __forceinline__ unsigned short f2bf_rne(float f) {
  unsigned int u = __float_as_uint(f);
  u += 0x7fffu + ((u >> 16) & 1u);
  return (unsigned short)(u >> 16);
}

// Streaming prepass: x [T][B][IN] fp32 -> xb same layout bf16; w -> wb bf16
// for SELECTED experts only (wb for unselected experts is never read by gemm).
__global__ __launch_bounds__(256) void convert_bf16(
    const float* __restrict__ x, const float* __restrict__ w,
    const int* __restrict__ sel,
    unsigned short* __restrict__ xb, unsigned short* __restrict__ wb) {
  const long tid = (long)blockIdx.x * blockDim.x + threadIdx.x;
  const long XV = (long)T_DIM * B_DIM * IN_DIM / 8;   // 2^21: block-aligned
  const float4* src;
  unsigned short* dst;
  long v;
  if (tid < XV) {
    v = tid; src = (const float4*)x; dst = xb;
  } else {
    v = tid - XV; src = (const float4*)w; dst = wb;
    // Expert of this block (2^17 vecs/expert; 256-vec blocks never straddle).
    const int e = (int)(v >> 17);
    __shared__ int used;
    if (threadIdx.x == 0) {
      int u = 0;
      #pragma unroll
      for (int i = 0; i < B_DIM * KSLOT; ++i) u |= (sel[i] == e) ? 1 : 0;
      used = u;
    }
    __syncthreads();
    if (!used) return;                 // whole block skips an unused expert
  }
  float4 a = src[2 * v];
  float4 c = src[2 * v + 1];
  ushort8 o;
  o[0] = f2bf_rne(a.x); o[1] = f2bf_rne(a.y); o[2] = f2bf_rne(a.z); o[3] = f2bf_rne(a.w);
  o[4] = f2bf_rne(c.x); o[5] = f2bf_rne(c.y); o[6] = f2bf_rne(c.z); o[7] = f2bf_rne(c.w);
  *(ushort8*)(dst + v * 8) = o;
}

// One 128x128 tile per block: C[t,o] = sum_i xb[t][b][i] * wb[sel[slot]][o][i]
// LDS row-major [rows][BK] staged as 16-B chunks with source-side XOR swizzle
// (slot s of row r holds colgrp s^(r&7)) -> ds_read_b128 conflict-free
// (verified 0 across R0-R3) while global_load_lds dests stay lane-contiguous.
__global__ __launch_bounds__(256, 4) void gemm_mod(
    const unsigned short* __restrict__ xb, const unsigned short* __restrict__ wb,
    const int* __restrict__ sel, float* __restrict__ out) {
  __shared__ alignas(16) unsigned short As[BM * BK];   // 16 KiB
  __shared__ alignas(16) unsigned short Bs[BN * BK];   // 16 KiB

  // XCD-chunked swizzle: HW round-robins consecutive blockIdx across 8 XCDs;
  // wgid = (bid%8)*256 + bid/8 gives each XCD one contiguous 256-tile chunk
  // = 2 full (b,ks) slots (2 experts = 4 MB bf16 -> fits the 4 MB XCD L2).
  const int wgid = (blockIdx.x & 7) * 256 + (blockIdx.x >> 3);
  const int slot = wgid >> 7;          // 0..15 = b*2+ks
  const int inner = wgid & 127;
  const int mt = inner >> 3;           // T tile:   0..15 (nt-major inside mt
  const int nt = inner & 7;            // OUT tile: 0..7   -> A-tile L2 reuse)
  const int b  = slot >> 1;
  const int ks = slot & 1;
  const int expert = sel[slot];

  const int AS_STRIDE = B_DIM * IN_DIM;  // 8192
  const unsigned short* A  = xb + ((long)mt * BM * B_DIM + b) * IN_DIM;
  const unsigned short* Bw = wb + ((long)expert * OUT_DIM + (long)nt * BN) * IN_DIM;

  const int tid  = threadIdx.x;
  const int lane = tid & 63;

  // A: 1024 chunks -> 4/thread.  B: 1024 chunks -> 4/thread.
  int aoff[4], boff[4], clds[4];
  #pragma unroll
  for (int j = 0; j < 4; ++j) {
    const int c = tid + j * 256;
    const int r = c >> 3;
    const int g = (c & 7) ^ (r & 7);
    aoff[j] = r * AS_STRIDE + g * 8;
    boff[j] = r * IN_DIM + g * 8;
    clds[j] = c * 8;
  }

  const int lm = lane & 15;            // MFMA m/n index
  const int kg = lane >> 4;            // MFMA k-group (0..3)
  const int rsw = lm & 7;              // row-derived swizzle term

  const int wave = tid >> 6;           // 4 waves: 2(M) x 2(N); wave tile 64x64
  const int wm = (wave >> 1) * 64;
  const int wn = (wave & 1) * 64;

  f32x4 acc[4][4];
  const f32x4 z = {0.f, 0.f, 0.f, 0.f};
  #pragma unroll
  for (int i = 0; i < 4; ++i)
    #pragma unroll
    for (int j = 0; j < 4; ++j) acc[i][j] = z;

  for (int kt = 0; kt < IN_DIM; kt += BK) {
    __syncthreads();                   // previous iter's ds_reads done before overwrite
    #pragma unroll
    for (int j = 0; j < 4; ++j)
      async_load16(A + aoff[j] + kt, &As[clds[j]]);
    #pragma unroll
    for (int j = 0; j < 4; ++j)
      async_load16(Bw + boff[j] + kt, &Bs[clds[j]]);
    __syncthreads();                   // drains vmcnt(0) before s_barrier

    #pragma unroll
    for (int kst = 0; kst < 2; ++kst) {  // two K=32 steps inside BK=64
      const int gsel = (kst * 4 + kg);
      bf16x8 af[4], bfr[4];
      #pragma unroll
      for (int mi = 0; mi < 4; ++mi) {
        const int row = wm + mi * 16 + lm;
        af[mi] = *(const bf16x8*)&As[(row * 8 + (gsel ^ rsw)) * 8];
      }
      #pragma unroll
      for (int ni = 0; ni < 4; ++ni) {
        const int row = wn + ni * 16 + lm;
        bfr[ni] = *(const bf16x8*)&Bs[(row * 8 + (gsel ^ rsw)) * 8];
      }
      #pragma unroll
      for (int mi = 0; mi < 4; ++mi)
        #pragma unroll
        for (int ni = 0; ni < 4; ++ni)
          acc[mi][ni] = __builtin_amdgcn_mfma_f32_16x16x32_bf16(af[mi], bfr[ni], acc[mi][ni], 0, 0, 0);
    }
  }

  // Epilogue. C/D layout (m89-verified): col = lane&15, row = (lane>>4)*4 + reg
  const int row0 = mt * BM + wm + kg * 4;
  const int col0 = nt * BN + wn + lm;
  #pragma unroll
  for (int mi = 0; mi < 4; ++mi) {
    #pragma unroll
    for (int r = 0; r < 4; ++r) {
      const int t = row0 + mi * 16 + r;
      float* po = out + (long)t * (B_DIM * KSLOT * OUT_DIM)
                      + b * (KSLOT * OUT_DIM) + ks * OUT_DIM + col0;
      #pragma unroll
      for (int ni = 0; ni < 4; ++ni)
        po[ni * 16] = acc[mi][ni][r];
    }
  }
}

extern "C" void kernel_launch(void* const* d_in, const int* in_sizes, int n_in,
                              void* d_out, int out_size, void* d_ws, size_t ws_size,
                              hipStream_t stream) {
  const float* x   = (const float*)d_in[0];   // [T][B][IN] fp32
  const int*   sel = (const int*)d_in[1];     // [B][K] int32
  const float* w   = (const float*)d_in[2];   // [NMOD][OUT][IN] fp32
  float* out = (float*)d_out;                 // [T][B][K*OUT] fp32

  unsigned short* xb = (unsigned short*)d_ws;                 // 32 MiB bf16 [T][B][IN]
  unsigned short* wb = xb + (long)T_DIM * B_DIM * IN_DIM;     // 32 MiB bf16 [NMOD][OUT][IN]

  const long total_vecs =
      ((long)T_DIM * B_DIM * IN_DIM + (long)NMOD * OUT_DIM * IN_DIM) / 8;
  convert_bf16<<<dim3((unsigned)((total_vecs + 255) / 256)), 256, 0, stream>>>(x, w, sel, xb, wb);

  // 2048 blocks (16 slots x 16 mt x 8 nt), 1D for the XCD swizzle.
  gemm_mod<<<dim3(2048), 256, 0, stream>>>(xb, wb, sel, out);
}